// Round 1
// baseline (4160.102 us; speedup 1.0000x reference)
//
#include <hip/hip_runtime.h>
#include <stdint.h>

// Problem constants (B,T,H,V) = (4,1024,2048,32000)
#define M_TOK 4096
#define N_VOC 32000
#define K_DIM 2048
#define BM 128
#define BN 128
#define BK 128
#define BETA 0.1f
#define W_SCALE 32.0f
#define INV_W_SCALE (1.0f / 32.0f)

typedef float f32x4 __attribute__((ext_vector_type(4)));
typedef int i32x4 __attribute__((ext_vector_type(4)));
typedef int i32x8 __attribute__((ext_vector_type(8)));

// fp32 -> fp8 e4m3 (OCP) cast with static scale.
// 16 B/lane fully-coalesced read (float4), 4 B/lane packed write.
__global__ __launch_bounds__(256) void cast_f32_fp8(const float* __restrict__ in,
                                                    unsigned* __restrict__ out, int n4,
                                                    float scale) {
  int i = blockIdx.x * blockDim.x + threadIdx.x;
  int stride = gridDim.x * blockDim.x;
  const float4* __restrict__ in4 = (const float4*)in;
  for (; i < n4; i += stride) {
    float4 f = in4[i];
    int v = __builtin_amdgcn_cvt_pk_fp8_f32(f.x * scale, f.y * scale, 0, false);
    v = __builtin_amdgcn_cvt_pk_fp8_f32(f.z * scale, f.w * scale, v, true);
    out[i] = (unsigned)v;
  }
}

// C = A(M,K) @ B(N,K)^T in fp8 e4m3 via MX-scaled MFMA (unit scales), reduced
// over N on the fly:
//   S[m] += sum_n exp(C[m,n]);  L[m] += sum_n C[m,n];  sel[m] = C[m, ids[m]]
//
// LDS rows are 128 fp8 = 8 x 16B chunks. XOR swizzle: global chunk cg of row r
// is stored at LDS chunk cg ^ (r&7). Staging (global_load_lds, linear LDS dest,
// pre-swizzled global source) and ds_read_b128 fragment reads (8 lanes per 16B
// bank column = the 8-phase floor) are both conflict-free.
__global__ __launch_bounds__(256) void gemm_stats(
    const unsigned char* __restrict__ A,   // [M_TOK][K_DIM] fp8
    const unsigned char* __restrict__ B,   // [N_VOC][K_DIM] fp8 (scaled by W_SCALE)
    const int* __restrict__ ids,           // [M_TOK]
    float* __restrict__ S, float* __restrict__ L, float* __restrict__ sel) {
  __shared__ unsigned char lA[BM * BK];  // 16 KB
  __shared__ unsigned char lB[BN * BK];  // 16 KB

  const int tid = threadIdx.x;
  const int wid = tid >> 6;
  const int lane = tid & 63;
  const int m0 = blockIdx.y * BM;
  const int n0 = blockIdx.x * BN;
  const int wr = wid >> 1, wc = wid & 1;  // wave 2x2 grid over 128x128 tile
  const int l15 = lane & 15, quad = lane >> 4;

  // staging coords: each global_load_lds call moves 64 lanes x 16B = 1KB = 8 rows
  const int sRow = lane >> 3;                       // 0..7 (row & 7 within stage)
  const int sCol = (((lane & 7) ^ sRow) << 4);      // swizzled SOURCE chunk byte

  // fragment read byte offsets within a row (loop-invariant):
  // lane needs global chunks 2*quad, 2*quad+1 of row (..+l15); phys = cg ^ (l15&7)
  const int swz = l15 & 7;
  const int cOff0 = (((2 * quad) ^ swz) << 4);
  const int cOff1 = (((2 * quad + 1) ^ swz) << 4);

  f32x4 acc[4][4];
  const f32x4 zero = {0.f, 0.f, 0.f, 0.f};
#pragma unroll
  for (int i = 0; i < 4; ++i)
#pragma unroll
    for (int j = 0; j < 4; ++j) acc[i][j] = zero;

  for (int k0 = 0; k0 < K_DIM; k0 += BK) {
#pragma unroll
    for (int q = 0; q < 4; ++q) {
      int seg = wid * 4 + q;        // 0..15, wave-uniform
      int row = seg * 8 + sRow;     // 0..127
      const unsigned char* ga = A + (size_t)(m0 + row) * K_DIM + k0 + sCol;
      const unsigned char* gb = B + (size_t)(n0 + row) * K_DIM + k0 + sCol;
      __builtin_amdgcn_global_load_lds(
          (const __attribute__((address_space(1))) unsigned int*)ga,
          (__attribute__((address_space(3))) unsigned int*)(&lA[seg * 1024]), 16, 0, 0);
      __builtin_amdgcn_global_load_lds(
          (const __attribute__((address_space(1))) unsigned int*)gb,
          (__attribute__((address_space(3))) unsigned int*)(&lB[seg * 1024]), 16, 0, 0);
    }
    __syncthreads();  // drains vmcnt before LDS reads

    i32x8 af[4];
#pragma unroll
    for (int i = 0; i < 4; ++i) {
      const unsigned char* base = &lA[(wr * 64 + i * 16 + l15) * BK];
      i32x4 lo = *(const i32x4*)(base + cOff0);
      i32x4 hi = *(const i32x4*)(base + cOff1);
      af[i] = __builtin_shufflevector(lo, hi, 0, 1, 2, 3, 4, 5, 6, 7);
    }
#pragma unroll
    for (int j = 0; j < 4; ++j) {
      const unsigned char* base = &lB[(wc * 64 + j * 16 + l15) * BK];
      i32x4 lo = *(const i32x4*)(base + cOff0);
      i32x4 hi = *(const i32x4*)(base + cOff1);
      i32x8 bf = __builtin_shufflevector(lo, hi, 0, 1, 2, 3, 4, 5, 6, 7);
#pragma unroll
      for (int i = 0; i < 4; ++i)
        acc[i][j] = __builtin_amdgcn_mfma_scale_f32_16x16x128_f8f6f4(
            af[i], bf, acc[i][j], 0, 0, 0, 0x7F7F7F7F, 0, 0x7F7F7F7F);
    }
    __syncthreads();
  }

  // Epilogue. C/D layout (shape-determined, m89/m121): col = lane&15, row = quad*4 + reg.
  // Lane owns rows {wr*64 + i*16 + quad*4 + r}, cols {n0 + wc*64 + j*16 + l15}.
  // Logits were computed against W*W_SCALE -> multiply by INV_W_SCALE.
#pragma unroll
  for (int i = 0; i < 4; ++i) {
#pragma unroll
    for (int r = 0; r < 4; ++r) {
      int row = m0 + wr * 64 + i * 16 + quad * 4 + r;
      int sid = ids[row];
      int loc = sid - n0 - wc * 64;
      bool hit = (loc >= 0) && (loc < 64) && ((loc & 15) == l15);
      float es = 0.f, ls = 0.f, selv = 0.f;
#pragma unroll
      for (int j = 0; j < 4; ++j) {
        float v = acc[i][j][r] * INV_W_SCALE;
        es += __expf(v);
        ls += v;
        if (hit && ((loc >> 4) == j)) selv = v;
      }
      if (hit) sel[row] = selv;  // unique writer across grid
      // butterfly across the quad's 16 lanes (masks < 16 stay in-group)
#pragma unroll
      for (int mk = 1; mk < 16; mk <<= 1) {
        es += __shfl_xor(es, mk);
        ls += __shfl_xor(ls, mk);
      }
      if (l15 == 0) {
        atomicAdd(&S[row], es);
        atomicAdd(&L[row], ls);
      }
    }
  }
}

__global__ __launch_bounds__(1024) void finalize_kernel(
    const float* __restrict__ S1, const float* __restrict__ L1, const float* __restrict__ P1,
    const float* __restrict__ S2, const float* __restrict__ P2,
    const float* __restrict__ mask, const float* __restrict__ adv, float* __restrict__ out) {
  __shared__ float red[12];
  int tid = threadIdx.x;
  int lane = tid & 63;
  if (tid < 12) red[tid] = 0.f;
  __syncthreads();

  float loss_num = 0.f, mask_sum = 0.f, ptl_sum = 0.f, lpm_sum = 0.f;
  float klb[4] = {0.f, 0.f, 0.f, 0.f}, mb[4] = {0.f, 0.f, 0.f, 0.f};
#pragma unroll
  for (int k = 0; k < 4; ++k) {
    int t = k * 1024 + tid;  // batch index b == k exactly
    float lse1 = logf(S1[t]);
    float ptl = P1[t] - lse1;
    float ref_ptl = P2[t] - logf(S2[t]);
    float d = ref_ptl - ptl;
    float kl = expf(d) - d - 1.f;
    float m = mask[t];
    float a = adv[k];
    // coef_1 = exp(ptl - stopgrad(ptl)) = 1; coef_2 = clip(1,...) = 1
    // per_token_loss = -min(adv, adv) + BETA*kl = -adv + BETA*kl
    loss_num += (-a + BETA * kl) * m;
    mask_sum += m;
    ptl_sum += ptl;
    lpm_sum += L1[t] * (1.f / (float)N_VOC) - lse1;
    klb[k] += kl * m;
    mb[k] += m;
  }
  float vals[12] = {loss_num, mask_sum, ptl_sum, lpm_sum,
                    klb[0], klb[1], klb[2], klb[3],
                    mb[0],  mb[1],  mb[2],  mb[3]};
#pragma unroll
  for (int v = 0; v < 12; ++v) {
    float xv = vals[v];
#pragma unroll
    for (int mk = 32; mk >= 1; mk >>= 1) xv += __shfl_xor(xv, mk);
    if (lane == 0) atomicAdd(&red[v], xv);
  }
  __syncthreads();
  if (tid == 0) {
    float loss = red[0] / fmaxf(red[1], 1.f);
    float km = 0.f;
#pragma unroll
    for (int b = 0; b < 4; ++b) km += red[4 + b] / fmaxf(red[8 + b], 1.f);
    out[0] = loss;                       // loss
    out[1] = red[2] * (1.f / 4096.f);    // per_token_logps.mean()
    out[2] = red[3] * (1.f / 4096.f);    // log_probs.mean()
    out[3] = km * 0.25f;                 // kl_metric
  }
}

extern "C" void kernel_launch(void* const* d_in, const int* in_sizes, int n_in,
                              void* d_out, int out_size, void* d_ws, size_t ws_size,
                              hipStream_t stream) {
  const float* x = (const float*)d_in[0];
  const float* W = (const float*)d_in[1];
  const float* ref_W = (const float*)d_in[2];
  const float* ref_x = (const float*)d_in[3];
  const int* ids = (const int*)d_in[4];
  const float* mask = (const float*)d_in[5];
  const float* adv = (const float*)d_in[6];
  float* out = (float*)d_out;

  // Workspace layout: [ Wq8 65.5MB | xq8 8.4MB | accum 96KB ]  (~74MB)
  char* ws = (char*)d_ws;
  unsigned char* Wq = (unsigned char*)ws;
  unsigned char* xq = (unsigned char*)(ws + (size_t)N_VOC * K_DIM);
  float* accum = (float*)(ws + (size_t)N_VOC * K_DIM + (size_t)M_TOK * K_DIM);
  float* S1 = accum;
  float* L1 = accum + 4096;
  float* P1 = accum + 8192;
  float* S2 = accum + 12288;
  float* L2 = accum + 16384;
  float* P2 = accum + 20480;

  hipMemsetAsync(accum, 0, 6 * 4096 * sizeof(float), stream);

  dim3 grid(N_VOC / BN, M_TOK / BM);  // 250 x 32

  cast_f32_fp8<<<2048, 256, 0, stream>>>(W, (unsigned*)Wq, N_VOC * K_DIM / 4, W_SCALE);
  cast_f32_fp8<<<512, 256, 0, stream>>>(x, (unsigned*)xq, M_TOK * K_DIM / 4, 1.0f);
  gemm_stats<<<grid, 256, 0, stream>>>(xq, Wq, ids, S1, L1, P1);

  // W buffer reused for ref (stream-ordered after gemm 1)
  cast_f32_fp8<<<2048, 256, 0, stream>>>(ref_W, (unsigned*)Wq, N_VOC * K_DIM / 4, W_SCALE);
  cast_f32_fp8<<<512, 256, 0, stream>>>(ref_x, (unsigned*)xq, M_TOK * K_DIM / 4, 1.0f);
  gemm_stats<<<grid, 256, 0, stream>>>(xq, Wq, ids, S2, L2, P2);

  finalize_kernel<<<1, 1024, 0, stream>>>(S1, L1, P1, S2, P2, mask, adv, out);
}

// Round 2
// 2039.875 us; speedup vs baseline: 2.0394x; 2.0394x over previous
//
#include <hip/hip_runtime.h>
#include <stdint.h>

// Problem constants (B,T,H,V) = (4,1024,2048,32000)
#define M_TOK 4096
#define N_VOC 32000
#define K_DIM 2048
#define BM 256
#define BN 256
#define BK 64
#define NT (K_DIM / BK)  // 32 K-tiles
#define BETA 0.1f
#define W_SCALE 32.0f
#define INV_W_SCALE (1.0f / 32.0f)

typedef float f32x4 __attribute__((ext_vector_type(4)));

// fp32 -> fp8 e4m3 (OCP) cast with static scale.
// 16 B/lane fully-coalesced read (float4), 4 B/lane packed write.
__global__ __launch_bounds__(256) void cast_f32_fp8(const float* __restrict__ in,
                                                    unsigned* __restrict__ out, int n4,
                                                    float scale) {
  int i = blockIdx.x * blockDim.x + threadIdx.x;
  int stride = gridDim.x * blockDim.x;
  const float4* __restrict__ in4 = (const float4*)in;
  for (; i < n4; i += stride) {
    float4 f = in4[i];
    int v = __builtin_amdgcn_cvt_pk_fp8_f32(f.x * scale, f.y * scale, 0, false);
    v = __builtin_amdgcn_cvt_pk_fp8_f32(f.z * scale, f.w * scale, v, true);
    out[i] = (unsigned)v;
  }
}

// C = A(M,K) @ B(N,K)^T in fp8 e4m3 (B pre-scaled by W_SCALE), reduced over N:
//   S[m] += sum_n exp(C[m,n]);  L[m] += sum_n C[m,n];  sel[m] = C[m, ids[m]]
//
// 256x256 tile, 8 waves (2M x 4N), deep pipeline with counted vmcnt (T3+T4):
// LDS = 2 buffers x (A 16KB + B 16KB) = 64KB. Each K-tile (BK=64) is staged as
// 2 "pieces"; piece p = the 32-byte k-slice [p*32, p*32+32) of all 256 rows,
// LDS layout [row][32B] (rows 32B apart -> b64 fragment reads are uniformly
// 4 dwords/bank = structural floor, no swizzle needed; global_load_lds dest is
// linear). Per phase: issue piece p of tile t+1, s_waitcnt vmcnt(4) (retires
// piece p of tile t, keeps 4 loads in flight across the barrier), raw
// s_barrier, 12 ds_read_b64, setprio(1) + 32 MFMA. vmcnt never drains to 0 in
// the main loop (tail: 2 -> 0).
__global__ __launch_bounds__(512, 2) void gemm_stats(
    const unsigned char* __restrict__ A,   // [M_TOK][K_DIM] fp8
    const unsigned char* __restrict__ B,   // [N_VOC][K_DIM] fp8 (scaled by W_SCALE)
    const int* __restrict__ ids,           // [M_TOK]
    float* __restrict__ S, float* __restrict__ L, float* __restrict__ sel) {
  __shared__ unsigned char lds[65536];  // [buf:2][mat:2][piece:2][256*32]

  const int tid = threadIdx.x;
  const int w = tid >> 6;     // wave 0..7
  const int l = tid & 63;
  const int m0 = blockIdx.y * BM;
  const int n0 = blockIdx.x * BN;
  const int wm = w >> 2, wn = w & 3;  // 2x4 wave grid; per-wave out = 128x64
  const int l15 = l & 15, quad = l >> 4;

  // Staging: wave w stages rows w*32..w*32+31 (2 lanes/row, 16B each).
  const unsigned char* pA = A + (size_t)(m0 + w * 32 + (l >> 1)) * K_DIM + (l & 1) * 16;
  const unsigned char* pB = B + (size_t)(n0 + w * 32 + (l >> 1)) * K_DIM + (l & 1) * 16;
  unsigned char* ldsA = &lds[w * 1024];           // + buf*32768 + p*8192
  unsigned char* ldsB = &lds[16384 + w * 1024];

  // Fragment read offsets (row*32 + quad*8 within a piece).
  const int ra = (wm * 128 + l15) * 32 + quad * 8;          // A: + i*512
  const int rb = 16384 + (wn * 64 + l15) * 32 + quad * 8;   // B: + j*512

  f32x4 acc[8][4];
  const f32x4 zero = {0.f, 0.f, 0.f, 0.f};
#pragma unroll
  for (int i = 0; i < 8; ++i)
#pragma unroll
    for (int j = 0; j < 4; ++j) acc[i][j] = zero;

#define STAGE(nb, p, kn)                                                                 \
  do {                                                                                   \
    __builtin_amdgcn_global_load_lds(                                                    \
        (const __attribute__((address_space(1))) unsigned int*)(pA + (kn) + (p) * 32),   \
        (__attribute__((address_space(3))) unsigned int*)(ldsA + (nb) * 32768 + (p) * 8192), \
        16, 0, 0);                                                                       \
    __builtin_amdgcn_global_load_lds(                                                    \
        (const __attribute__((address_space(1))) unsigned int*)(pB + (kn) + (p) * 32),   \
        (__attribute__((address_space(3))) unsigned int*)(ldsB + (nb) * 32768 + (p) * 8192), \
        16, 0, 0);                                                                       \
  } while (0)

#define PHASE(bf, p)                                                                     \
  do {                                                                                   \
    const unsigned char* Ab = &lds[(bf) * 32768 + (p) * 8192] + ra;                      \
    const unsigned char* Bb = &lds[(bf) * 32768 + (p) * 8192] + rb;                      \
    long long af[8], bq[4];                                                              \
    _Pragma("unroll") for (int i = 0; i < 8; ++i)                                        \
        af[i] = *(const long long*)(Ab + i * 512);                                       \
    _Pragma("unroll") for (int j = 0; j < 4; ++j)                                        \
        bq[j] = *(const long long*)(Bb + j * 512);                                       \
    __builtin_amdgcn_s_setprio(1);                                                       \
    _Pragma("unroll") for (int i = 0; i < 8; ++i)                                        \
      _Pragma("unroll") for (int j = 0; j < 4; ++j)                                      \
        acc[i][j] = __builtin_amdgcn_mfma_f32_16x16x32_fp8_fp8(af[i], bq[j],             \
                                                               acc[i][j], 0, 0, 0);      \
    __builtin_amdgcn_s_setprio(0);                                                       \
  } while (0)

  // Prologue: stage both pieces of tile 0 into buffer 0 (4 loads in flight).
  STAGE(0, 0, 0);
  STAGE(0, 1, 0);

  for (int t = 0; t < NT - 1; ++t) {
    const int bf = t & 1, nb = bf ^ 1;
    const int kn = (t + 1) * BK;
    STAGE(nb, 0, kn);
    asm volatile("s_waitcnt vmcnt(4)" ::: "memory");  // piece 0 of tile t landed
    __builtin_amdgcn_s_barrier();
    asm volatile("" ::: "memory");
    PHASE(bf, 0);
    STAGE(nb, 1, kn);
    asm volatile("s_waitcnt vmcnt(4)" ::: "memory");  // piece 1 of tile t landed
    __builtin_amdgcn_s_barrier();
    asm volatile("" ::: "memory");
    PHASE(bf, 1);
  }
  // Tail: tile NT-1 sits in buffer 1; drain 2 -> 0.
  asm volatile("s_waitcnt vmcnt(2)" ::: "memory");
  __builtin_amdgcn_s_barrier();
  asm volatile("" ::: "memory");
  PHASE(1, 0);
  asm volatile("s_waitcnt vmcnt(0)" ::: "memory");
  __builtin_amdgcn_s_barrier();
  asm volatile("" ::: "memory");
  PHASE(1, 1);

#undef STAGE
#undef PHASE

  // Epilogue. C/D layout (m89/m121): col = lane&15, row = quad*4 + reg.
  // Lane owns rows {wm*128 + i*16 + quad*4 + r}, cols {n0 + wn*64 + j*16 + l15}.
  // Logits were computed against W*W_SCALE -> multiply by INV_W_SCALE.
#pragma unroll
  for (int i = 0; i < 8; ++i) {
#pragma unroll
    for (int r = 0; r < 4; ++r) {
      int row = m0 + wm * 128 + i * 16 + quad * 4 + r;
      int sid = ids[row];
      int loc = sid - n0 - wn * 64;
      bool hit = (loc >= 0) && (loc < 64) && ((loc & 15) == l15);
      float es = 0.f, ls = 0.f, selv = 0.f;
#pragma unroll
      for (int j = 0; j < 4; ++j) {
        float v = acc[i][j][r] * INV_W_SCALE;
        es += __expf(v);
        ls += v;
        if (hit && ((loc >> 4) == j)) selv = v;
      }
      if (hit) sel[row] = selv;  // unique writer across grid
      // butterfly across the quad's 16 lanes (masks < 16 stay in-group)
#pragma unroll
      for (int mk = 1; mk < 16; mk <<= 1) {
        es += __shfl_xor(es, mk);
        ls += __shfl_xor(ls, mk);
      }
      if (l15 == 0) {
        atomicAdd(&S[row], es);
        atomicAdd(&L[row], ls);
      }
    }
  }
}

__global__ __launch_bounds__(1024) void finalize_kernel(
    const float* __restrict__ S1, const float* __restrict__ L1, const float* __restrict__ P1,
    const float* __restrict__ S2, const float* __restrict__ P2,
    const float* __restrict__ mask, const float* __restrict__ adv, float* __restrict__ out) {
  __shared__ float red[12];
  int tid = threadIdx.x;
  int lane = tid & 63;
  if (tid < 12) red[tid] = 0.f;
  __syncthreads();

  float loss_num = 0.f, mask_sum = 0.f, ptl_sum = 0.f, lpm_sum = 0.f;
  float klb[4] = {0.f, 0.f, 0.f, 0.f}, mb[4] = {0.f, 0.f, 0.f, 0.f};
#pragma unroll
  for (int k = 0; k < 4; ++k) {
    int t = k * 1024 + tid;  // batch index b == k exactly
    float lse1 = logf(S1[t]);
    float ptl = P1[t] - lse1;
    float ref_ptl = P2[t] - logf(S2[t]);
    float d = ref_ptl - ptl;
    float kl = expf(d) - d - 1.f;
    float m = mask[t];
    float a = adv[k];
    // coef_1 = exp(ptl - stopgrad(ptl)) = 1; coef_2 = clip(1,...) = 1
    // per_token_loss = -min(adv, adv) + BETA*kl = -adv + BETA*kl
    loss_num += (-a + BETA * kl) * m;
    mask_sum += m;
    ptl_sum += ptl;
    lpm_sum += L1[t] * (1.f / (float)N_VOC) - lse1;
    klb[k] += kl * m;
    mb[k] += m;
  }
  float vals[12] = {loss_num, mask_sum, ptl_sum, lpm_sum,
                    klb[0], klb[1], klb[2], klb[3],
                    mb[0],  mb[1],  mb[2],  mb[3]};
#pragma unroll
  for (int v = 0; v < 12; ++v) {
    float xv = vals[v];
#pragma unroll
    for (int mk = 32; mk >= 1; mk >>= 1) xv += __shfl_xor(xv, mk);
    if (lane == 0) atomicAdd(&red[v], xv);
  }
  __syncthreads();
  if (tid == 0) {
    float loss = red[0] / fmaxf(red[1], 1.f);
    float km = 0.f;
#pragma unroll
    for (int b = 0; b < 4; ++b) km += red[4 + b] / fmaxf(red[8 + b], 1.f);
    out[0] = loss;                       // loss
    out[1] = red[2] * (1.f / 4096.f);    // per_token_logps.mean()
    out[2] = red[3] * (1.f / 4096.f);    // log_probs.mean()
    out[3] = km * 0.25f;                 // kl_metric
  }
}

extern "C" void kernel_launch(void* const* d_in, const int* in_sizes, int n_in,
                              void* d_out, int out_size, void* d_ws, size_t ws_size,
                              hipStream_t stream) {
  const float* x = (const float*)d_in[0];
  const float* W = (const float*)d_in[1];
  const float* ref_W = (const float*)d_in[2];
  const float* ref_x = (const float*)d_in[3];
  const int* ids = (const int*)d_in[4];
  const float* mask = (const float*)d_in[5];
  const float* adv = (const float*)d_in[6];
  float* out = (float*)d_out;

  // Workspace layout: [ Wq8 65.5MB | xq8 8.4MB | accum 96KB ]  (~74MB)
  char* ws = (char*)d_ws;
  unsigned char* Wq = (unsigned char*)ws;
  unsigned char* xq = (unsigned char*)(ws + (size_t)N_VOC * K_DIM);
  float* accum = (float*)(ws + (size_t)N_VOC * K_DIM + (size_t)M_TOK * K_DIM);
  float* S1 = accum;
  float* L1 = accum + 4096;
  float* P1 = accum + 8192;
  float* S2 = accum + 12288;
  float* L2 = accum + 16384;
  float* P2 = accum + 20480;

  hipMemsetAsync(accum, 0, 6 * 4096 * sizeof(float), stream);

  dim3 grid(N_VOC / BN, M_TOK / BM);  // 125 x 16

  cast_f32_fp8<<<2048, 256, 0, stream>>>(W, (unsigned*)Wq, N_VOC * K_DIM / 4, W_SCALE);
  cast_f32_fp8<<<512, 256, 0, stream>>>(x, (unsigned*)xq, M_TOK * K_DIM / 4, 1.0f);
  gemm_stats<<<grid, 512, 0, stream>>>(xq, Wq, ids, S1, L1, P1);

  // W buffer reused for ref (stream-ordered after gemm 1)
  cast_f32_fp8<<<2048, 256, 0, stream>>>(ref_W, (unsigned*)Wq, N_VOC * K_DIM / 4, W_SCALE);
  cast_f32_fp8<<<512, 256, 0, stream>>>(ref_x, (unsigned*)xq, M_TOK * K_DIM / 4, 1.0f);
  gemm_stats<<<grid, 512, 0, stream>>>(xq, Wq, ids, S2, L2, P2);

  finalize_kernel<<<1, 1024, 0, stream>>>(S1, L1, P1, S2, P2, mask, adv, out);
}

// Round 3
// 1745.433 us; speedup vs baseline: 2.3834x; 1.1687x over previous
//
#include <hip/hip_runtime.h>
#include <stdint.h>

// Problem constants (B,T,H,V) = (4,1024,2048,32000)
#define M_TOK 4096
#define N_VOC 32000
#define K_DIM 2048
#define BM 256
#define BN 256
#define BK 64
#define NT (K_DIM / BK)  // 32 K-tiles
#define BETA 0.1f
#define W_SCALE 32.0f
#define INV_W_SCALE (1.0f / 32.0f)

typedef float f32x4 __attribute__((ext_vector_type(4)));

// fp32 -> fp8 e4m3 (OCP) cast with static scale.
// 16 B/lane fully-coalesced read (float4), 4 B/lane packed write.
__global__ __launch_bounds__(256) void cast_f32_fp8(const float* __restrict__ in,
                                                    unsigned* __restrict__ out, int n4,
                                                    float scale) {
  int i = blockIdx.x * blockDim.x + threadIdx.x;
  int stride = gridDim.x * blockDim.x;
  const float4* __restrict__ in4 = (const float4*)in;
  for (; i < n4; i += stride) {
    float4 f = in4[i];
    int v = __builtin_amdgcn_cvt_pk_fp8_f32(f.x * scale, f.y * scale, 0, false);
    v = __builtin_amdgcn_cvt_pk_fp8_f32(f.z * scale, f.w * scale, v, true);
    out[i] = (unsigned)v;
  }
}

// C = A(M,K) @ B(N,K)^T in fp8 e4m3 (B pre-scaled by W_SCALE), reduced over N:
//   S[m] += sum_n exp(C[m,n]);  L[m] += sum_n C[m,n];  sel[m] = C[m, ids[m]]
//
// 256x256 tile, 8 waves (2M x 4N). LDS: 2 buffers x (A 16KB | B 16KB) = 64KB.
// A K-tile row is 64B = 4 x 16B chunks; chunk c of row r is stored at phys
// chunk c ^ (r&3) ^ ((r>>2)&3). This swizzle makes every half-wave of the
// ds_read_b64 fragment reads cover all 32 banks at exactly 2 accesses/bank
// (the free level), and is applied identically on the staging SOURCE address
// (global_load_lds dest stays linear) and the read address (rule #21).
//
// Pipeline (1 barrier/K-tile, issue-early/wait-late): per tile t we wait
// vmcnt(0) on tile t's 4 loads (issued two MFMA-phases earlier, ~1300 cyc of
// compute in between -> wait is pre-satisfied), barrier (also closes the
// write-after-read hazard on buffer nb), then issue tile t+1's A-stages,
// compute phase 0, issue B-stages, compute phase 1.
__global__ __launch_bounds__(512, 2) void gemm_stats(
    const unsigned char* __restrict__ A,   // [M_TOK][K_DIM] fp8
    const unsigned char* __restrict__ B,   // [N_VOC][K_DIM] fp8 (scaled by W_SCALE)
    const int* __restrict__ ids,           // [M_TOK]
    float* __restrict__ S, float* __restrict__ L, float* __restrict__ sel) {
  __shared__ unsigned char lds[65536];  // [buf:2][mat:2][block:16][1KB]

  const int tid = threadIdx.x;
  const int w = tid >> 6;     // wave 0..7
  const int l = tid & 63;
  const int m0 = blockIdx.y * BM;
  const int n0 = blockIdx.x * BN;
  const int wm = w >> 2, wn = w & 3;  // 2x4 wave grid; per-wave out = 128x64
  const int l15 = l & 15, quad = l >> 4;

  // Staging: wave w stages rows w*32..w*32+31 of A and B (2 blocks of 16 rows
  // each, 1KB per block). Lane l covers (row srow, phys chunk l&3) whose
  // logical chunk is sc -> pre-swizzled global source.
  const int srow = l >> 2;                                   // 0..15
  const int sc = (l & 3) ^ (srow & 3) ^ ((srow >> 2) & 3);   // logical 16B chunk
  const size_t sOff = (size_t)srow * K_DIM + (size_t)(sc * 16);
  const unsigned char* pA = A + (size_t)(m0 + w * 32) * K_DIM + sOff;
  const unsigned char* pB = B + (size_t)(n0 + w * 32) * K_DIM + sOff;
  const size_t RS16 = (size_t)16 * K_DIM;  // 16-row stride

  unsigned char* dA = &lds[w * 2048];           // + nb*32768 (+1024 for 2nd block)
  unsigned char* dB = &lds[16384 + w * 2048];

  // Fragment read offset: row l15 (within 16-row block), logical chunk
  // c = p*2 + (quad>>1), phys chunk = c ^ sw, sub-offset (quad&1)*8.
  const int sw = (l15 & 3) ^ ((l15 >> 2) & 3);
  const int roff = l15 * 64 + (((quad >> 1) ^ sw) << 4) + (quad & 1) * 8;  // p=0; p=1: ^32

  f32x4 acc[8][4];
  const f32x4 zero = {0.f, 0.f, 0.f, 0.f};
#pragma unroll
  for (int i = 0; i < 8; ++i)
#pragma unroll
    for (int j = 0; j < 4; ++j) acc[i][j] = zero;

#define GLL(src, dst)                                                              \
  __builtin_amdgcn_global_load_lds(                                                \
      (const __attribute__((address_space(1))) unsigned int*)(src),                \
      (__attribute__((address_space(3))) unsigned int*)(dst), 16, 0, 0)

#define STAGE_A(nb, kn)                                                            \
  do {                                                                            \
    GLL(pA + (kn), dA + (nb)*32768);                                              \
    GLL(pA + (kn) + RS16, dA + (nb)*32768 + 1024);                                \
  } while (0)

#define STAGE_B(nb, kn)                                                            \
  do {                                                                            \
    GLL(pB + (kn), dB + (nb)*32768);                                              \
    GLL(pB + (kn) + RS16, dB + (nb)*32768 + 1024);                                \
  } while (0)

#define PHASE(bf, p)                                                               \
  do {                                                                            \
    const unsigned char* Abase = &lds[(bf)*32768 + wm*8192];                       \
    const unsigned char* Bbase = &lds[(bf)*32768 + 16384 + wn*4096];               \
    const int ro = roff ^ ((p) << 5);                                              \
    long long af[8], bq[4];                                                        \
    _Pragma("unroll") for (int i = 0; i < 8; ++i)                                  \
        af[i] = *(const long long*)(Abase + i * 1024 + ro);                        \
    _Pragma("unroll") for (int j = 0; j < 4; ++j)                                  \
        bq[j] = *(const long long*)(Bbase + j * 1024 + ro);                        \
    __builtin_amdgcn_s_setprio(1);                                                 \
    _Pragma("unroll") for (int i = 0; i < 8; ++i)                                  \
      _Pragma("unroll") for (int j = 0; j < 4; ++j)                                \
        acc[i][j] = __builtin_amdgcn_mfma_f32_16x16x32_fp8_fp8(af[i], bq[j],       \
                                                               acc[i][j], 0, 0, 0);\
    __builtin_amdgcn_s_setprio(0);                                                 \
  } while (0)

  // Prologue: stage tile 0 into buffer 0 (4 loads in flight).
  STAGE_A(0, 0);
  STAGE_B(0, 0);

  for (int t = 0; t < NT - 1; ++t) {
    const int bf = t & 1, nb = bf ^ 1;
    const int kn = (t + 1) * BK;
    asm volatile("s_waitcnt vmcnt(0)" ::: "memory");  // tile t landed (issued 2 phases ago)
    __builtin_amdgcn_s_barrier();
    asm volatile("" ::: "memory");
    STAGE_A(nb, kn);
    PHASE(bf, 0);
    STAGE_B(nb, kn);
    PHASE(bf, 1);
  }
  // Tail: tile NT-1 sits in buffer 1.
  asm volatile("s_waitcnt vmcnt(0)" ::: "memory");
  __builtin_amdgcn_s_barrier();
  asm volatile("" ::: "memory");
  PHASE(1, 0);
  PHASE(1, 1);

#undef GLL
#undef STAGE_A
#undef STAGE_B
#undef PHASE

  // Epilogue. C/D layout (m89/m121): col = lane&15, row = quad*4 + reg.
  // Lane owns rows {wm*128 + i*16 + quad*4 + r}, cols {n0 + wn*64 + j*16 + l15}.
  // Logits were computed against W*W_SCALE -> multiply by INV_W_SCALE.
#pragma unroll
  for (int i = 0; i < 8; ++i) {
#pragma unroll
    for (int r = 0; r < 4; ++r) {
      int row = m0 + wm * 128 + i * 16 + quad * 4 + r;
      int sid = ids[row];
      int loc = sid - n0 - wn * 64;
      bool hit = (loc >= 0) && (loc < 64) && ((loc & 15) == l15);
      float es = 0.f, ls = 0.f, selv = 0.f;
#pragma unroll
      for (int j = 0; j < 4; ++j) {
        float v = acc[i][j][r] * INV_W_SCALE;
        es += __expf(v);
        ls += v;
        if (hit && ((loc >> 4) == j)) selv = v;
      }
      if (hit) sel[row] = selv;  // unique writer across grid
      // butterfly across the quad's 16 lanes (masks < 16 stay in-group)
#pragma unroll
      for (int mk = 1; mk < 16; mk <<= 1) {
        es += __shfl_xor(es, mk);
        ls += __shfl_xor(ls, mk);
      }
      if (l15 == 0) {
        atomicAdd(&S[row], es);
        atomicAdd(&L[row], ls);
      }
    }
  }
}

__global__ __launch_bounds__(1024) void finalize_kernel(
    const float* __restrict__ S1, const float* __restrict__ L1, const float* __restrict__ P1,
    const float* __restrict__ S2, const float* __restrict__ P2,
    const float* __restrict__ mask, const float* __restrict__ adv, float* __restrict__ out) {
  __shared__ float red[12];
  int tid = threadIdx.x;
  int lane = tid & 63;
  if (tid < 12) red[tid] = 0.f;
  __syncthreads();

  float loss_num = 0.f, mask_sum = 0.f, ptl_sum = 0.f, lpm_sum = 0.f;
  float klb[4] = {0.f, 0.f, 0.f, 0.f}, mb[4] = {0.f, 0.f, 0.f, 0.f};
#pragma unroll
  for (int k = 0; k < 4; ++k) {
    int t = k * 1024 + tid;  // batch index b == k exactly
    float lse1 = logf(S1[t]);
    float ptl = P1[t] - lse1;
    float ref_ptl = P2[t] - logf(S2[t]);
    float d = ref_ptl - ptl;
    float kl = expf(d) - d - 1.f;
    float m = mask[t];
    float a = adv[k];
    // coef_1 = exp(ptl - stopgrad(ptl)) = 1; coef_2 = clip(1,...) = 1
    // per_token_loss = -min(adv, adv) + BETA*kl = -adv + BETA*kl
    loss_num += (-a + BETA * kl) * m;
    mask_sum += m;
    ptl_sum += ptl;
    lpm_sum += L1[t] * (1.f / (float)N_VOC) - lse1;
    klb[k] += kl * m;
    mb[k] += m;
  }
  float vals[12] = {loss_num, mask_sum, ptl_sum, lpm_sum,
                    klb[0], klb[1], klb[2], klb[3],
                    mb[0],  mb[1],  mb[2],  mb[3]};
#pragma unroll
  for (int v = 0; v < 12; ++v) {
    float xv = vals[v];
#pragma unroll
    for (int mk = 32; mk >= 1; mk >>= 1) xv += __shfl_xor(xv, mk);
    if (lane == 0) atomicAdd(&red[v], xv);
  }
  __syncthreads();
  if (tid == 0) {
    float loss = red[0] / fmaxf(red[1], 1.f);
    float km = 0.f;
#pragma unroll
    for (int b = 0; b < 4; ++b) km += red[4 + b] / fmaxf(red[8 + b], 1.f);
    out[0] = loss;                       // loss
    out[1] = red[2] * (1.f / 4096.f);    // per_token_logps.mean()
    out[2] = red[3] * (1.f / 4096.f);    // log_probs.mean()
    out[3] = km * 0.25f;                 // kl_metric
  }
}

extern "C" void kernel_launch(void* const* d_in, const int* in_sizes, int n_in,
                              void* d_out, int out_size, void* d_ws, size_t ws_size,
                              hipStream_t stream) {
  const float* x = (const float*)d_in[0];
  const float* W = (const float*)d_in[1];
  const float* ref_W = (const float*)d_in[2];
  const float* ref_x = (const float*)d_in[3];
  const int* ids = (const int*)d_in[4];
  const float* mask = (const float*)d_in[5];
  const float* adv = (const float*)d_in[6];
  float* out = (float*)d_out;

  // Workspace layout: [ Wq8 65.5MB | xq8 8.4MB | accum 96KB ]  (~74MB)
  char* ws = (char*)d_ws;
  unsigned char* Wq = (unsigned char*)ws;
  unsigned char* xq = (unsigned char*)(ws + (size_t)N_VOC * K_DIM);
  float* accum = (float*)(ws + (size_t)N_VOC * K_DIM + (size_t)M_TOK * K_DIM);
  float* S1 = accum;
  float* L1 = accum + 4096;
  float* P1 = accum + 8192;
  float* S2 = accum + 12288;
  float* L2 = accum + 16384;
  float* P2 = accum + 20480;

  hipMemsetAsync(accum, 0, 6 * 4096 * sizeof(float), stream);

  dim3 grid(N_VOC / BN, M_TOK / BM);  // 125 x 16

  cast_f32_fp8<<<2048, 256, 0, stream>>>(W, (unsigned*)Wq, N_VOC * K_DIM / 4, W_SCALE);
  cast_f32_fp8<<<512, 256, 0, stream>>>(x, (unsigned*)xq, M_TOK * K_DIM / 4, 1.0f);
  gemm_stats<<<grid, 512, 0, stream>>>(xq, Wq, ids, S1, L1, P1);

  // W buffer reused for ref (stream-ordered after gemm 1)
  cast_f32_fp8<<<2048, 256, 0, stream>>>(ref_W, (unsigned*)Wq, N_VOC * K_DIM / 4, W_SCALE);
  cast_f32_fp8<<<512, 256, 0, stream>>>(ref_x, (unsigned*)xq, M_TOK * K_DIM / 4, 1.0f);
  gemm_stats<<<grid, 512, 0, stream>>>(xq, Wq, ids, S2, L2, P2);

  finalize_kernel<<<1, 1024, 0, stream>>>(S1, L1, P1, S2, P2, mask, adv, out);
}